// Round 2
// baseline (273.550 us; speedup 1.0000x reference)
//
#include <hip/hip_runtime.h>
#include <hip/hip_bf16.h>

// X = Z * G, G = (I - tril(A_raw,-1))^{-1} (unit lower-triangular 256x256)
// Z: [131072 x 256] fp32, Out: [131072 x 256] fp32.
//
// make_G3 (unchanged): 256 blocks, right-looking solve, readlane broadcast.
// scm_gemm5: same 512x512 shape as gemm4 but FULL-ITERATION software pipeline:
//   zA/zB hold both K-halves of iter i; each pack consumes loads issued one
//   full iteration ago and immediately reloads the freed regs for iter i+1.
//   => every s_waitcnt has >=40 newer VMEM ops behind it (vmcnt(~46), never
//   vmcnt(0)) so stores are never drained and load latency is fully hidden.
//   N-half pairing: blocks m and m+256 (same Z rows) share a CU -> 2nd Z
//   read hits L1/L2. Out stores nontemporal (write-once).

typedef __bf16 bf16x8 __attribute__((ext_vector_type(8)));
typedef float f32x4 __attribute__((ext_vector_type(4)));

__device__ __forceinline__ unsigned short f2bf(float f) {
    union { float f; unsigned u; } v; v.f = f;
    unsigned u = v.u;
    u += 0x7FFFu + ((u >> 16) & 1u);   // RNE
    return (unsigned short)(u >> 16);
}
__device__ __forceinline__ bf16x8 pack8(float4 a, float4 b) {
    union { bf16x8 v; __hip_bfloat162 h[4]; } u;
    u.h[0] = __float22bfloat162_rn(make_float2(a.x, a.y));
    u.h[1] = __float22bfloat162_rn(make_float2(a.z, a.w));
    u.h[2] = __float22bfloat162_rn(make_float2(b.x, b.y));
    u.h[3] = __float22bfloat162_rn(make_float2(b.z, b.w));
    return u.v;
}

// ---------------------------------------------------------------------------
// Kernel 1: G columns, one block per column (unchanged).
// ---------------------------------------------------------------------------
#define AST 258
__global__ __launch_bounds__(256) void make_G3(const float* __restrict__ A,
                                               unsigned short* __restrict__ Gt) {
    __shared__ unsigned short As[256 * AST];   // 129 KB
    const int tid = threadIdx.x;
    const int l = tid & 63;
    const int wv = tid >> 6;

    for (int it = 0; it < 64; ++it) {
        const int r = it * 4 + wv;
        const int c0 = l * 4;
        float4 v = *(const float4*)(A + r * 256 + c0);
        *(ushort2*)(&As[r * AST + c0])     = make_ushort2(f2bf(v.x), f2bf(v.y));
        *(ushort2*)(&As[r * AST + c0 + 2]) = make_ushort2(f2bf(v.z), f2bf(v.w));
    }
    __syncthreads();
    if (wv != 0) return;

    const int c = blockIdx.x;
    float p[4];
#pragma unroll
    for (int k = 0; k < 4; ++k) p[k] = (64 * k + l == c) ? 1.f : 0.f;

#pragma unroll
    for (int kb = 0; kb < 4; ++kb) {
#pragma unroll 8
        for (int i2 = 0; i2 < 32; ++i2) {
            unsigned u[4];
#pragma unroll
            for (int k = 0; k < 4; ++k)
                if (k >= kb)
                    u[k] = *(const unsigned*)(&As[(64 * k + l) * AST + kb * 64 + 2 * i2]);
            const int t0 = 2 * i2, t1 = t0 + 1;
            float s0 = __int_as_float(__builtin_amdgcn_readlane(__float_as_int(p[kb]), t0));
            p[kb] += (l > t0 ? __int_as_float(u[kb] << 16) : 0.f) * s0;
#pragma unroll
            for (int k = 0; k < 4; ++k)
                if (k > kb) p[k] += __int_as_float(u[k] << 16) * s0;
            float s1 = __int_as_float(__builtin_amdgcn_readlane(__float_as_int(p[kb]), t1));
            p[kb] += (l > t1 ? __int_as_float(u[kb] & 0xffff0000u) : 0.f) * s1;
#pragma unroll
            for (int k = 0; k < 4; ++k)
                if (k > kb) p[k] += __int_as_float(u[k] & 0xffff0000u) * s1;
        }
    }
#pragma unroll
    for (int k = 0; k < 4; ++k)
        Gt[c * 256 + 64 * k + l] = f2bf(p[k]);
}

// ---------------------------------------------------------------------------
// Kernel 2: Out = Z @ G. 512 blocks (256 M-tiles x 2 N-halves) x 512 thr.
// ---------------------------------------------------------------------------
__global__ __launch_bounds__(512, 4) void scm_gemm5(const float* __restrict__ Z,
                                                    const unsigned short* __restrict__ Gt,
                                                    float* __restrict__ Out) {
    __shared__ __align__(16) unsigned short Gs[128 * 256];   // 64 KB
    const int tid = threadIdx.x;
    const int lane = tid & 63;
    const int wave = tid >> 6;
    const int n = lane & 15;
    const int quad = lane >> 4;
    // N-half in the HIGH bit: blocks m and m+256 read identical Z rows and
    // land on the same CU (same %256 dispatch slot) -> 2nd read is L1/L2-hot.
    const int bn = (blockIdx.x >> 8) * 128;
    const size_t blockRow = (size_t)(blockIdx.x & 255) * 512;

    // ---- stage G half (64 KB): 4096 granules / 512 thr = 8 each ----
#pragma unroll
    for (int it = 0; it < 8; ++it) {
        const int chunk = it * 512 + tid;
        const int row = chunk >> 5;            // local col 0..127
        const int g = chunk & 31;
        const int gs = g ^ (row & 7);
        uint4 v = *(const uint4*)(Gt + (bn + row) * 256 + g * 8);
        *(uint4*)(&Gs[row * 256 + gs * 8]) = v;
    }
    __syncthreads();

    const int swz = n & 7;
    const float* zbase = Z + (blockRow + wave * 16 + n) * 256 + quad * 8;
    float* obase = Out + (blockRow + wave * 16 + quad * 4) * 256 + bn + n;

    f32x4 acc[8];
#pragma unroll
    for (int nt = 0; nt < 8; ++nt) {
        f32x4 zero = {0.f, 0.f, 0.f, 0.f};
        acc[nt] = zero;
    }

    // Full-iteration prefetch buffers: zA = K-lo half, zB = K-hi half.
    float4 zA[8], zB[8];
#pragma unroll
    for (int kk = 0; kk < 4; ++kk) {
        zA[2 * kk]     = *(const float4*)(zbase + kk * 32);
        zA[2 * kk + 1] = *(const float4*)(zbase + kk * 32 + 4);
    }
#pragma unroll
    for (int kk = 0; kk < 4; ++kk) {
        zB[2 * kk]     = *(const float4*)(zbase + 128 + kk * 32);
        zB[2 * kk + 1] = *(const float4*)(zbase + 128 + kk * 32 + 4);
    }

#pragma unroll
    for (int i = 0; i < 4; ++i) {
        const bool pf = (i < 3);
        const float* zn = zbase + (size_t)((i < 3) ? (i + 1) : 0) * 128 * 256;

        // ---- K-lo: pack (waits on loads issued 1 iter ago), reload freed
        //      regs for iter i+1, then 8 MFMAs ----
#pragma unroll
        for (int kk = 0; kk < 4; ++kk) {
            bf16x8 af = pack8(zA[2 * kk], zA[2 * kk + 1]);
            if (pf) {
                zA[2 * kk]     = *(const float4*)(zn + kk * 32);
                zA[2 * kk + 1] = *(const float4*)(zn + kk * 32 + 4);
            }
#pragma unroll
            for (int nt = 0; nt < 8; ++nt) {
                const bf16x8 b = *(const bf16x8*)(
                    &Gs[(nt * 16 + n) * 256 + ((kk * 4 + quad) ^ swz) * 8]);
                acc[nt] = __builtin_amdgcn_mfma_f32_16x16x32_bf16(af, b, acc[nt], 0, 0, 0);
            }
        }
        // ---- K-hi ----
#pragma unroll
        for (int kk = 0; kk < 4; ++kk) {
            bf16x8 af = pack8(zB[2 * kk], zB[2 * kk + 1]);
            if (pf) {
                zB[2 * kk]     = *(const float4*)(zn + 128 + kk * 32);
                zB[2 * kk + 1] = *(const float4*)(zn + 128 + kk * 32 + 4);
            }
#pragma unroll
            for (int nt = 0; nt < 8; ++nt) {
                const bf16x8 b = *(const bf16x8*)(
                    &Gs[(nt * 16 + n) * 256 + ((16 + kk * 4 + quad) ^ swz) * 8]);
                acc[nt] = __builtin_amdgcn_mfma_f32_16x16x32_bf16(af, b, acc[nt], 0, 0, 0);
            }
        }
        // ---- store + re-zero. C/D layout: col = lane&15, row = quad*4 + r.
        //      Nontemporal: Out is write-once, keep L2/LLC for the Z stream.
        float* oi = obase + (size_t)i * 128 * 256;
#pragma unroll
        for (int nt = 0; nt < 8; ++nt)
#pragma unroll
            for (int r = 0; r < 4; ++r) {
                __builtin_nontemporal_store(acc[nt][r], &oi[(size_t)r * 256 + nt * 16]);
                acc[nt][r] = 0.f;
            }
    }
}

extern "C" void kernel_launch(void* const* d_in, const int* in_sizes, int n_in,
                              void* d_out, int out_size, void* d_ws, size_t ws_size,
                              hipStream_t stream) {
    const float* Z = (const float*)d_in[0];       // [131072 x 256]
    const float* A = (const float*)d_in[1];       // [256 x 256]
    float* Out = (float*)d_out;                   // [131072 x 256]
    unsigned short* Gt = (unsigned short*)d_ws;   // 256*256 bf16 = 128 KB

    hipLaunchKernelGGL(make_G3, dim3(256), dim3(256), 0, stream, A, Gt);
    hipLaunchKernelGGL(scm_gemm5, dim3(512), dim3(512), 0, stream, Z, Gt, Out);
}